// Round 1
// 664.214 us; speedup vs baseline: 1.0757x; 1.0757x over previous
//
#include <hip/hip_runtime.h>
#include <math.h>

// Problem constants (match reference)
constexpr int BB = 2048;
constexpr int PP = 16;
constexpr int NN = 128;
constexpr int DD = 512;
constexpr float INV_TEMP = 10.0f;   // 1 / 0.1
constexpr float EPSV = 1e-8f;

__device__ __forceinline__ float dp4(const float4& a, const float4& b) {
    return a.x * b.x + a.y * b.y + a.z * b.z + a.w * b.w;
}

// One block per anchor b. 256 threads = 4 waves.
// Quarter-wave layout: each 16-lane group owns one row at a time.
// Lane sl in a group holds float4 indices {sl + 16*j, j=0..7} of the row
// -> each load instruction reads 4 rows x 256 B contiguous segments.
// Row reduction = 4 butterfly steps within the 16-lane group.
//
// NEW: masked-out negatives (neg_mask == 0, ~50% of rows) contribute
// exp(-inf)=0 to the LSE, so we skip their 2 KB row loads entirely.
// The mask row is staged in LDS once per block; each wave hoists its 8
// per-iteration mask values into registers so the branch decision never
// stalls the 8-deep load pipeline. Branch is uniform per 16-lane quarter,
// so excluded quarters issue no global loads (exec-masked) -> negative
// traffic drops from 512 MB to ~258 MB.
__global__ __launch_bounds__(256, 4) void ntxent_kernel(
    const float* __restrict__ target,      // [B, D]
    const float* __restrict__ positives,   // [B, P, D]
    const float* __restrict__ negatives,   // [B, N, D]
    const int* __restrict__ pos_idx,       // [B]
    const int* __restrict__ neg_mask,      // [B, N] (harness widens bool->int32)
    float* __restrict__ out)               // [1]
{
    const int b    = blockIdx.x;
    const int tid  = threadIdx.x;
    const int wave = tid >> 6;
    const int lane = tid & 63;
    const int sub  = lane >> 4;   // quarter-wave id 0..3
    const int sl   = lane & 15;   // lane within quarter

    __shared__ float s_logit[NN];
    __shared__ int   s_mask[NN];

    // ---- stage the mask row (512 B) into LDS
    if (tid < NN) s_mask[tid] = neg_mask[(size_t)b * NN + tid];

    // ---- target fragment: lane holds t4[sl + 16*j], j=0..7 (full row per quarter)
    const float4* t4 = (const float4*)(target + (size_t)b * DD);
    float4 treg[8];
    #pragma unroll
    for (int j = 0; j < 8; ++j) treg[j] = t4[sl + 16 * j];

    float t2 = 0.f;
    #pragma unroll
    for (int j = 0; j < 8; ++j) t2 += dp4(treg[j], treg[j]);
    #pragma unroll
    for (int m = 1; m < 16; m <<= 1) t2 += __shfl_xor(t2, m, 64);
    const float tn = sqrtf(t2);   // full ||t|| in every lane

    // ---- gathered positive: wave 0 only (each quarter redundantly, L1-hot)
    float pos_logit = 0.f;
    if (wave == 0) {
        const int pidx = pos_idx[b];
        const float4* p4 = (const float4*)(positives + ((size_t)b * PP + pidx) * DD);
        float pd = 0.f, p2 = 0.f;
        #pragma unroll
        for (int j = 0; j < 8; ++j) {
            const float4 a = p4[sl + 16 * j];
            pd += dp4(treg[j], a);
            p2 += dp4(a, a);
        }
        #pragma unroll
        for (int m = 1; m < 16; m <<= 1) {
            pd += __shfl_xor(pd, m, 64);
            p2 += __shfl_xor(p2, m, 64);
        }
        pos_logit = pd / fmaxf(tn * sqrtf(p2), EPSV) * INV_TEMP;  // uniform in wave 0
    }

    __syncthreads();   // s_mask ready

    // ---- hoist this wave's 8 mask values into registers (no LDS latency in loop)
    int mreg[8];
    #pragma unroll
    for (int i = 0; i < 8; ++i) mreg[i] = s_mask[wave * 32 + i * 4 + sub];

    // ---- negatives: wave w owns rows [w*32, w*32+32); 4 rows per iteration
    const float* nbase = negatives + (size_t)b * NN * DD;

    for (int i = 0; i < 8; ++i) {
        const int row = wave * 32 + i * 4 + sub;
        if (mreg[i]) {
            const float4* nr = (const float4*)(nbase + (size_t)row * DD);
            float4 a[8];
            #pragma unroll
            for (int j = 0; j < 8; ++j) a[j] = nr[sl + 16 * j];   // 8 loads in flight
            float dot = 0.f, n2 = 0.f;
            #pragma unroll
            for (int j = 0; j < 8; ++j) {
                dot += dp4(treg[j], a[j]);
                n2  += dp4(a[j], a[j]);
            }
            #pragma unroll
            for (int m = 1; m < 16; m <<= 1) {      // reduce within 16-lane group
                dot += __shfl_xor(dot, m, 64);
                n2  += __shfl_xor(n2, m, 64);
            }
            if (sl == 0)
                s_logit[row] = dot / fmaxf(tn * sqrtf(n2), EPSV) * INV_TEMP;
        } else {
            if (sl == 0)
                s_logit[row] = -INFINITY;   // excluded => contributes 0 to LSE
        }
    }
    __syncthreads();

    // ---- masked logsumexp over [pos_logit, s_logit[0..127]] on wave 0
    if (wave == 0) {
        const float x0 = s_logit[lane];
        const float x1 = s_logit[lane + 64];
        float m = fmaxf(fmaxf(x0, x1), pos_logit);
        #pragma unroll
        for (int off = 32; off > 0; off >>= 1) m = fmaxf(m, __shfl_xor(m, off, 64));
        float s = expf(x0 - m) + expf(x1 - m);   // exp(-inf) = 0 handles mask
        if (lane == 0) s += expf(pos_logit - m); // positive always included
        #pragma unroll
        for (int off = 32; off > 0; off >>= 1) s += __shfl_xor(s, off, 64);
        if (lane == 0) {
            const float lse  = m + logf(s);
            const float loss = lse - pos_logit;
            atomicAdd(out, loss * (1.0f / (float)BB));
        }
    }
}

extern "C" void kernel_launch(void* const* d_in, const int* in_sizes, int n_in,
                              void* d_out, int out_size, void* d_ws, size_t ws_size,
                              hipStream_t stream) {
    const float* target    = (const float*)d_in[0];
    const float* positives = (const float*)d_in[1];
    const float* negatives = (const float*)d_in[2];
    const int*   pos_idx   = (const int*)d_in[3];
    const int*   neg_mask  = (const int*)d_in[4];
    float* out = (float*)d_out;

    // Harness re-poisons d_out with 0xAA before every timed replay.
    hipMemsetAsync(out, 0, sizeof(float), stream);

    ntxent_kernel<<<BB, 256, 0, stream>>>(target, positives, negatives,
                                          pos_idx, neg_mask, out);
}